// Round 4
// baseline (15277.998 us; speedup 1.0000x reference)
//
#include <hip/hip_runtime.h>
#include <cstddef>

// Problem constants
#define BB 4
#define TT 512
#define EE 1024
#define G4 4096      // 4*EE
#define VV 32000
#define EOSI 31999
#define LOG_BOUND (-1.0005003335835335e-3f)  // log(0.999)
#define NBLK 256     // persistent grid: 256 blocks x 256 threads, all co-resident

__device__ __forceinline__ float softplusf(float x) {
  return fmaxf(x, 0.0f) + log1pf(expf(-fabsf(x)));
}
__device__ __forceinline__ float sigmoidf(float x) {
  return 1.0f / (1.0f + expf(-x));
}

// Zero the flag array (ws is poisoned 0xAA before every call).
__global__ void init_state(unsigned* flag) {
  flag[threadIdx.x] = 0u;   // one block of 256
}

// C[M,N] = Arows[M,K] @ Bw[N,K]^T + bias1[n] + bias2[n]
// mode 0: A row = m (A base pre-offset by caller)
// mode 1: A row = tokens[b*512 + t] with m = t*4+b   (embedding gather)
// mode 2: A row = t*4 + b + 4 with m = b*512+t       (h1 buffer -> logits layout)
// Tile 128x128, BK=16, 8x8 per thread, f32.
__global__ __launch_bounds__(256) void gemm_nt(
    const float* __restrict__ A, const float* __restrict__ Bw,
    float* __restrict__ C, int M, int N, int K,
    const float* __restrict__ bias1, const float* __restrict__ bias2,
    const int* __restrict__ tokens, int mode)
{
  __shared__ float As[16][132];   // [k][row], pad 132 to break bank conflicts
  __shared__ float Bs[16][132];
  const int tid  = threadIdx.x;
  const int bcol = blockIdx.x * 128;
  const int brow = blockIdx.y * 128;

  const int idx0 = tid, idx1 = tid + 256;
  const int ar0 = idx0 >> 2, ak0 = (idx0 & 3) * 4;
  const int ar1 = idx1 >> 2, ak1 = (idx1 & 3) * 4;

  long arow0, arow1;
  {
    int m0 = brow + ar0, m1 = brow + ar1;
    if (mode == 1) {
      arow0 = tokens[((m0 & 3) << 9) + (m0 >> 2)];
      arow1 = tokens[((m1 & 3) << 9) + (m1 >> 2)];
    } else if (mode == 2) {
      arow0 = ((m0 & 511) << 2) + (m0 >> 9) + 4;
      arow1 = ((m1 & 511) << 2) + (m1 >> 9) + 4;
    } else {
      arow0 = m0; arow1 = m1;
    }
  }
  const long brw0 = bcol + ar0, brw1 = bcol + ar1;

  float acc[8][8];
  #pragma unroll
  for (int i = 0; i < 8; ++i)
    #pragma unroll
    for (int j = 0; j < 8; ++j) acc[i][j] = 0.f;

  const int ti = tid >> 4, tj = tid & 15;

  for (int k0 = 0; k0 < K; k0 += 16) {
    float4 a0 = *(const float4*)(A  + arow0 * (long)K + k0 + ak0);
    float4 a1 = *(const float4*)(A  + arow1 * (long)K + k0 + ak1);
    float4 b0 = *(const float4*)(Bw + brw0  * (long)K + k0 + ak0);
    float4 b1 = *(const float4*)(Bw + brw1  * (long)K + k0 + ak1);
    __syncthreads();
    As[ak0+0][ar0] = a0.x; As[ak0+1][ar0] = a0.y; As[ak0+2][ar0] = a0.z; As[ak0+3][ar0] = a0.w;
    As[ak1+0][ar1] = a1.x; As[ak1+1][ar1] = a1.y; As[ak1+2][ar1] = a1.z; As[ak1+3][ar1] = a1.w;
    Bs[ak0+0][ar0] = b0.x; Bs[ak0+1][ar0] = b0.y; Bs[ak0+2][ar0] = b0.z; Bs[ak0+3][ar0] = b0.w;
    Bs[ak1+0][ar1] = b1.x; Bs[ak1+1][ar1] = b1.y; Bs[ak1+2][ar1] = b1.z; Bs[ak1+3][ar1] = b1.w;
    __syncthreads();
    #pragma unroll
    for (int kk = 0; kk < 16; ++kk) {
      float af[8], bf[8];
      #pragma unroll
      for (int i = 0; i < 8; ++i) af[i] = As[kk][ti*8 + i];
      #pragma unroll
      for (int j = 0; j < 8; ++j) bf[j] = Bs[kk][tj*8 + j];
      #pragma unroll
      for (int i = 0; i < 8; ++i)
        #pragma unroll
        for (int j = 0; j < 8; ++j) acc[i][j] += af[i] * bf[j];
    }
  }

  float bv[8];
  #pragma unroll
  for (int jj = 0; jj < 8; ++jj) {
    int n = bcol + tj*8 + jj;
    float bb = 0.f;
    if (bias1) bb += bias1[n];
    if (bias2) bb += bias2[n];
    bv[jj] = bb;
  }
  #pragma unroll
  for (int i = 0; i < 8; ++i) {
    int m = brow + ti*8 + i;
    float* cp = C + (size_t)m * N + bcol + tj*8;
    float4 v0 = make_float4(acc[i][0]+bv[0], acc[i][1]+bv[1], acc[i][2]+bv[2], acc[i][3]+bv[3]);
    float4 v1 = make_float4(acc[i][4]+bv[4], acc[i][5]+bv[5], acc[i][6]+bv[6], acc[i][7]+bv[7]);
    *(float4*)cp = v0;
    *(float4*)(cp + 4) = v1;
  }
}

// ---------------------------------------------------------------------------
// Merged 2-layer persistent LSTM, lag-1 pipeline: combined step tt computes
// h0[tt+1] = LSTM0(h0[tt]) and h1[tt] = LSTM1(h1[tt-1], x=h0[tt]), so ONE
// grid exchange serves both layers, and the Wih1 matvec (formerly a separate
// GEMM) is fused as a third dot-block sharing the h0 LDS reads.
//
// 256 blocks x 256 threads; block owns 4 dims of each layer -> 48 weight rows
// (16 Whh0 + 16 Wih1 + 16 Whh1) in REGISTERS (192 VGPR/thread for weights).
// Thread = (rl in [0,16) rows, ks in [0,16) interleaved k-slices).
//
// Exchange (round-2-proven mechanism): RELAXED agent-scope atomics only for
// all cross-block data -> no cache-maintenance storms; h/flag stores ordered
// by s_waitcnt vmcnt(0); flattened poll (one flag per thread); h staged back
// via relaxed agent-scope 8B atomic loads (IF-fresh by construction).
// Co-residency: LDS 33 KB + ~230 VGPR -> >=1 block/CU; grid 256 <= capacity.
// ---------------------------------------------------------------------------
__global__ __launch_bounds__(256, 1) void lstm2_persist(
    const float* __restrict__ g0pre,  // [t][b][gate*1024+j], t-stride 16384
    const float* __restrict__ Whh0,   // (4096,1024)
    const float* __restrict__ Wih1,   // (4096,1024)
    const float* __restrict__ Whh1,   // (4096,1024)
    const float* __restrict__ bih1,
    const float* __restrict__ bhh1,
    float* __restrict__ h0seq,        // 513 slots of (4,1024)
    float* __restrict__ h1seq,        // 513 slots of (4,1024)
    unsigned* __restrict__ flag)      // 256 flags, zeroed by init_state
{
  __shared__ float hl0[4096];         // h0[tt]   [b][k]  (16 KB)
  __shared__ float hl1[4096];         // h1[tt-1] [b][k]  (16 KB)
  __shared__ float gsum[48][4];       // [row][b]: 0..15 Whh0, 16..31 Wih1, 32..47 Whh1

  const int tid = threadIdx.x;
  const int bid = blockIdx.x;
  const int rl = tid >> 4, ks = tid & 15;   // local row 0..15, k-split 0..15
  const int grow = (rl >> 2) * 1024 + bid * 4 + (rl & 3);  // gate*1024 + dim

  // --- one-time: weight slices into registers (interleaved: float4 i*16+ks) ---
  float4 w0[16], wi1[16], wh1[16];
  {
    const float4* r0 = (const float4*)(Whh0 + (size_t)grow * 1024);
    const float4* r1 = (const float4*)(Wih1 + (size_t)grow * 1024);
    const float4* r2 = (const float4*)(Whh1 + (size_t)grow * 1024);
    #pragma unroll
    for (int i = 0; i < 16; ++i) {
      w0[i]  = r0[i * 16 + ks];
      wi1[i] = r1[i * 16 + ks];
      wh1[i] = r2[i * 16 + ks];
    }
  }
  // h0[0] = h1[-1] = 0 in LDS
  {
    float4 z = make_float4(0.f, 0.f, 0.f, 0.f);
    float4* a = (float4*)hl0; float4* b = (float4*)hl1;
    #pragma unroll
    for (int i = 0; i < 4; ++i) { a[tid + 256*i] = z; b[tid + 256*i] = z; }
  }

  // gate-lane state: lanes 0..15 = layer0 (b=q>>2, dim=q&3), 16..31 = layer1
  float creg = 0.f;
  const int q = tid & 15, gb = q >> 2, gj = q & 3;
  float gpv0 = 0.f, gpv1 = 0.f, gpv2 = 0.f, gpv3 = 0.f;   // layer0 gpre slice
  float bs0 = 0.f, bs1 = 0.f, bs2 = 0.f, bs3 = 0.f;       // layer1 biases
  if (tid < 16) {
    const float* gp = g0pre + (size_t)gb * 4096 + bid * 4 + gj;
    gpv0 = gp[0]; gpv1 = gp[1024]; gpv2 = gp[2048]; gpv3 = gp[3072];
  } else if (tid < 32) {
    int o = bid * 4 + gj;
    bs0 = bih1[o]        + bhh1[o];
    bs1 = bih1[1024 + o] + bhh1[1024 + o];
    bs2 = bih1[2048 + o] + bhh1[2048 + o];
    bs3 = bih1[3072 + o] + bhh1[3072 + o];
  }
  __syncthreads();

  const float4* h04 = (const float4*)hl0;
  const float4* h14 = (const float4*)hl1;

  for (int tt = 0; tt <= 512; ++tt) {
    // --- 3 dot-blocks: Whh0.h0, Wih1.h0 (shared reads), Whh1.h1 ---
    float a00=0.f,a01=0.f,a02=0.f,a03=0.f;
    float a10=0.f,a11=0.f,a12=0.f,a13=0.f;
    float a20=0.f,a21=0.f,a22=0.f,a23=0.f;
    #pragma unroll
    for (int i = 0; i < 16; ++i) {
      const int k4 = i * 16 + ks;
      float4 x0 = h04[k4], x1 = h04[256+k4], x2 = h04[512+k4], x3 = h04[768+k4];
      float4 y0 = h14[k4], y1 = h14[256+k4], y2 = h14[512+k4], y3 = h14[768+k4];
      float4 w = w0[i];
      a00 += w.x*x0.x + w.y*x0.y + w.z*x0.z + w.w*x0.w;
      a01 += w.x*x1.x + w.y*x1.y + w.z*x1.z + w.w*x1.w;
      a02 += w.x*x2.x + w.y*x2.y + w.z*x2.z + w.w*x2.w;
      a03 += w.x*x3.x + w.y*x3.y + w.z*x3.z + w.w*x3.w;
      w = wi1[i];
      a10 += w.x*x0.x + w.y*x0.y + w.z*x0.z + w.w*x0.w;
      a11 += w.x*x1.x + w.y*x1.y + w.z*x1.z + w.w*x1.w;
      a12 += w.x*x2.x + w.y*x2.y + w.z*x2.z + w.w*x2.w;
      a13 += w.x*x3.x + w.y*x3.y + w.z*x3.z + w.w*x3.w;
      w = wh1[i];
      a20 += w.x*y0.x + w.y*y0.y + w.z*y0.z + w.w*y0.w;
      a21 += w.x*y1.x + w.y*y1.y + w.z*y1.z + w.w*y1.w;
      a22 += w.x*y2.x + w.y*y2.y + w.z*y2.z + w.w*y2.w;
      a23 += w.x*y3.x + w.y*y3.y + w.z*y3.z + w.w*y3.w;
    }
    // reduce across the 16 ks-lanes (xor 8,4,2,1 stays in 16-lane groups)
    #pragma unroll
    for (int m = 8; m >= 1; m >>= 1) {
      a00 += __shfl_xor(a00, m, 64); a01 += __shfl_xor(a01, m, 64);
      a02 += __shfl_xor(a02, m, 64); a03 += __shfl_xor(a03, m, 64);
      a10 += __shfl_xor(a10, m, 64); a11 += __shfl_xor(a11, m, 64);
      a12 += __shfl_xor(a12, m, 64); a13 += __shfl_xor(a13, m, 64);
      a20 += __shfl_xor(a20, m, 64); a21 += __shfl_xor(a21, m, 64);
      a22 += __shfl_xor(a22, m, 64); a23 += __shfl_xor(a23, m, 64);
    }
    if (ks == 0) {
      *(float4*)&gsum[     rl][0] = make_float4(a00, a01, a02, a03);
      *(float4*)&gsum[16 + rl][0] = make_float4(a10, a11, a12, a13);
      *(float4*)&gsum[32 + rl][0] = make_float4(a20, a21, a22, a23);
    }
    __syncthreads();                               // gsum ready

    // --- gates + state + h stores (wave 0, lanes 0..31) ---
    if (tid < 16) {
      if (tt < 512) {
        float gi = gpv0 + gsum[     gj][gb];
        float gf = gpv1 + gsum[ 4 + gj][gb];
        float gg = gpv2 + gsum[ 8 + gj][gb];
        float go = gpv3 + gsum[12 + gj][gb];
        float c = sigmoidf(gf) * creg + sigmoidf(gi) * tanhf(gg);
        creg = c;
        float hv = sigmoidf(go) * tanhf(c);
        __hip_atomic_store(h0seq + (size_t)(tt + 1) * G4 + gb * 1024 + bid * 4 + gj,
                           hv, __ATOMIC_RELAXED, __HIP_MEMORY_SCOPE_AGENT);
      }
    } else if (tid < 32) {
      if (tt >= 1) {
        float gi = bs0 + gsum[16 + gj][gb] + gsum[32 + gj][gb];
        float gf = bs1 + gsum[20 + gj][gb] + gsum[36 + gj][gb];
        float gg = bs2 + gsum[24 + gj][gb] + gsum[40 + gj][gb];
        float go = bs3 + gsum[28 + gj][gb] + gsum[44 + gj][gb];
        float c = sigmoidf(gf) * creg + sigmoidf(gi) * tanhf(gg);
        creg = c;
        float hv = sigmoidf(go) * tanhf(c);
        __hip_atomic_store(h1seq + (size_t)tt * G4 + gb * 1024 + bid * 4 + gj,
                           hv, __ATOMIC_RELAXED, __HIP_MEMORY_SCOPE_AGENT);
      }
    }

    if (tt == 512) break;   // final h1[512] stored; kernel-end drains vmcnt

    // --- arrival (wave 0) + g0 prefetch + flattened poll (all threads) ---
    if (tid < 64) {
      asm volatile("s_waitcnt vmcnt(0)" ::: "memory");   // h stores acked at IF
      if (tid == 0)
        __hip_atomic_store(flag + bid, (unsigned)(tt + 1),
                           __ATOMIC_RELAXED, __HIP_MEMORY_SCOPE_AGENT);
    }
    if (tid < 16 && tt + 1 < 512) {   // prefetch next g0 slice (plain cached)
      const float* gp = g0pre + (size_t)(tt + 1) * 16384 + (size_t)gb * 4096 + bid * 4 + gj;
      gpv0 = gp[0]; gpv1 = gp[1024]; gpv2 = gp[2048]; gpv3 = gp[3072];
      asm volatile("" ::: "memory");
    }
    {
      const unsigned tgt = (unsigned)(tt + 1);
      for (;;) {
        unsigned f = __hip_atomic_load(flag + tid, __ATOMIC_RELAXED, __HIP_MEMORY_SCOPE_AGENT);
        if (__all(f >= tgt)) break;
      }
    }
    asm volatile("" ::: "memory");
    __syncthreads();                               // all 256 flags seen

    // --- stage h0[tt+1] and h1[tt] via bypass 8B atomic loads (IF-fresh) ---
    {
      const unsigned long long* s0 =
          (const unsigned long long*)(h0seq + (size_t)(tt + 1) * G4);
      unsigned long long* d0 = (unsigned long long*)hl0;
      #pragma unroll
      for (int i = 0; i < 8; ++i)
        d0[tid + 256*i] = __hip_atomic_load(s0 + tid + 256*i,
                                            __ATOMIC_RELAXED, __HIP_MEMORY_SCOPE_AGENT);
      if (tt >= 1) {
        const unsigned long long* s1 =
            (const unsigned long long*)(h1seq + (size_t)tt * G4);
        unsigned long long* d1 = (unsigned long long*)hl1;
        #pragma unroll
        for (int i = 0; i < 8; ++i)
          d1[tid + 256*i] = __hip_atomic_load(s1 + tid + 256*i,
                                              __ATOMIC_RELAXED, __HIP_MEMORY_SCOPE_AGENT);
      }
    }
    __syncthreads();                               // hl0/hl1 current
  }
}

// Per-row (b,t) stats over logits in d_out:
__global__ __launch_bounds__(256) void row_stats(
    const float* __restrict__ logits, float* __restrict__ rowA, float* __restrict__ rowE)
{
  const int m = blockIdx.x;
  const float* row = logits + (size_t)m * VV;
  __shared__ float red[8];
  const int tid = threadIdx.x;

  float mx = -3.0e38f;
  for (int v = tid; v < EOSI; v += 256) mx = fmaxf(mx, row[v]);
  for (int off = 32; off; off >>= 1) mx = fmaxf(mx, __shfl_down(mx, off, 64));
  if ((tid & 63) == 0) red[tid >> 6] = mx;
  __syncthreads();
  if (tid == 0) red[4] = fmaxf(fmaxf(red[0], red[1]), fmaxf(red[2], red[3]));
  __syncthreads();
  mx = red[4];

  float s = 0.f;
  for (int v = tid; v < EOSI; v += 256) s += expf(row[v] - mx);
  for (int off = 32; off; off >>= 1) s += __shfl_down(s, off, 64);
  if ((tid & 63) == 0) red[tid >> 6] = s;
  __syncthreads();

  if (tid == 0) {
    s = red[0] + red[1] + red[2] + red[3];
    float lse_v = mx + logf(s);
    float eos = row[EOSI];
    int t = m & 511;                         // m = b*512 + t
    float log_lb = (float)(t + 1) * LOG_BOUND;
    float log_eos_lb = -softplusf(eos);      // log_sigmoid(-eos)
    float log_eos_ub = -softplusf(-eos);     // log_sigmoid(eos)
    float shift = log_lb + log_eos_lb;
    float f_lb = -expm1f(log_lb);            // 1 - exp(log_lb)
    float log_lb_eos = logf(f_lb) + log_eos_lb;
    float lprob_eos = log_lb_eos + softplusf(log_eos_ub - log_lb_eos);
    float aa = shift, bb = lprob_eos;
    float lse2 = fmaxf(aa, bb) + log1pf(expf(-fabsf(aa - bb)));
    rowA[m] = lse_v + lse2 - shift;
    rowE[m] = lprob_eos - lse2;
  }
}

// out[m][v] = logit - rowA[m] for v < EOSI ; rowE[m] at v == EOSI. In-place, float4.
__global__ __launch_bounds__(256) void finalize(
    float* __restrict__ out, const float* __restrict__ rowA, const float* __restrict__ rowE)
{
  const int m = blockIdx.y;
  const int v4 = blockIdx.x * 256 + threadIdx.x;   // 8000 float4 per row
  if (v4 >= 8000) return;
  float4* rp = (float4*)(out + (size_t)m * VV);
  const float A = rowA[m];
  float4 p = rp[v4];
  p.x -= A; p.y -= A; p.z -= A; p.w -= A;
  if (v4 == 7999) p.w = rowE[m];
  rp[v4] = p;
}

extern "C" void kernel_launch(void* const* d_in, const int* in_sizes, int n_in,
                              void* d_out, int out_size, void* d_ws, size_t ws_size,
                              hipStream_t stream)
{
  const int*   tokens = (const int*)  d_in[0];
  const float* emb    = (const float*)d_in[1];
  const float* Wproj  = (const float*)d_in[2];
  const float* Wih0   = (const float*)d_in[3];
  const float* Whh0   = (const float*)d_in[4];
  const float* bih0   = (const float*)d_in[5];
  const float* bhh0   = (const float*)d_in[6];
  const float* Wih1   = (const float*)d_in[7];
  const float* Whh1   = (const float*)d_in[8];
  const float* bih1   = (const float*)d_in[9];
  const float* bhh1   = (const float*)d_in[10];
  float* out = (float*)d_out;

  // workspace layout (floats): ~50 MB total
  float* ws = (float*)d_ws;
  float* g0   = ws;                        // 2048 x 4096
  float* h0   = g0 + (size_t)2048*4096;    // 513 slots of (4,1024); slot 0 unused
  float* h1   = h0 + (size_t)513*4096;
  unsigned* flag = (unsigned*)(h1 + (size_t)513*4096);   // 256
  float* rowA = (float*)(flag + 256);      // 2048
  float* rowE = rowA + 2048;

  init_state<<<1, 256, 0, stream>>>(flag);

  // layer 0 input gates for all (t,b): emb[tokens] @ Wih0^T + bih0 + bhh0
  gemm_nt<<<dim3(32, 16), 256, 0, stream>>>(emb, Wih0, g0, 2048, 4096, 1024,
                                            bih0, bhh0, tokens, 1);

  // both LSTM layers, lag-1 pipelined, single persistent launch
  lstm2_persist<<<NBLK, 256, 0, stream>>>(g0, Whh0, Wih1, Whh1, bih1, bhh1,
                                          h0, h1, flag);

  // projection: logits into d_out, layout (b, t, v)
  gemm_nt<<<dim3(250, 16), 256, 0, stream>>>(h1, Wproj, out, 2048, 32000, 1024,
                                             nullptr, nullptr, nullptr, 2);

  row_stats<<<2048, 256, 0, stream>>>(out, rowA, rowE);
  finalize<<<dim3(32, 2048), 256, 0, stream>>>(out, rowA, rowE);
}

// Round 5
// 12859.991 us; speedup vs baseline: 1.1880x; 1.1880x over previous
//
#include <hip/hip_runtime.h>
#include <cstddef>

// Problem constants
#define BB 4
#define TT 512
#define EE 1024
#define G4 4096      // 4*EE
#define VV 32000
#define EOSI 31999
#define LOG_BOUND (-1.0005003335835335e-3f)  // log(0.999)
#define NBLK 256     // persistent grid: 256 blocks x 256 threads, all co-resident

__device__ __forceinline__ float softplusf(float x) {
  return fmaxf(x, 0.0f) + log1pf(expf(-fabsf(x)));
}
__device__ __forceinline__ float sigmoidf(float x) {
  return 1.0f / (1.0f + expf(-x));
}

// Zero the flag array (ws is poisoned 0xAA before every call).
__global__ void init_state(unsigned* flag) {
  flag[threadIdx.x] = 0u;   // one block of 256
}

// C[M,N] = Arows[M,K] @ Bw[N,K]^T + bias1[n] + bias2[n]
// mode 0: A row = m (A base pre-offset by caller)
// mode 1: A row = tokens[b*512 + t] with m = t*4+b   (embedding gather)
// mode 2: A row = t*4 + b + 4 with m = b*512+t       (h1 buffer -> logits layout)
// Tile 128x128, BK=16, 8x8 per thread, f32.
__global__ __launch_bounds__(256) void gemm_nt(
    const float* __restrict__ A, const float* __restrict__ Bw,
    float* __restrict__ C, int M, int N, int K,
    const float* __restrict__ bias1, const float* __restrict__ bias2,
    const int* __restrict__ tokens, int mode)
{
  __shared__ float As[16][132];   // [k][row], pad 132 to break bank conflicts
  __shared__ float Bs[16][132];
  const int tid  = threadIdx.x;
  const int bcol = blockIdx.x * 128;
  const int brow = blockIdx.y * 128;

  const int idx0 = tid, idx1 = tid + 256;
  const int ar0 = idx0 >> 2, ak0 = (idx0 & 3) * 4;
  const int ar1 = idx1 >> 2, ak1 = (idx1 & 3) * 4;

  long arow0, arow1;
  {
    int m0 = brow + ar0, m1 = brow + ar1;
    if (mode == 1) {
      arow0 = tokens[((m0 & 3) << 9) + (m0 >> 2)];
      arow1 = tokens[((m1 & 3) << 9) + (m1 >> 2)];
    } else if (mode == 2) {
      arow0 = ((m0 & 511) << 2) + (m0 >> 9) + 4;
      arow1 = ((m1 & 511) << 2) + (m1 >> 9) + 4;
    } else {
      arow0 = m0; arow1 = m1;
    }
  }
  const long brw0 = bcol + ar0, brw1 = bcol + ar1;

  float acc[8][8];
  #pragma unroll
  for (int i = 0; i < 8; ++i)
    #pragma unroll
    for (int j = 0; j < 8; ++j) acc[i][j] = 0.f;

  const int ti = tid >> 4, tj = tid & 15;

  for (int k0 = 0; k0 < K; k0 += 16) {
    float4 a0 = *(const float4*)(A  + arow0 * (long)K + k0 + ak0);
    float4 a1 = *(const float4*)(A  + arow1 * (long)K + k0 + ak1);
    float4 b0 = *(const float4*)(Bw + brw0  * (long)K + k0 + ak0);
    float4 b1 = *(const float4*)(Bw + brw1  * (long)K + k0 + ak1);
    __syncthreads();
    As[ak0+0][ar0] = a0.x; As[ak0+1][ar0] = a0.y; As[ak0+2][ar0] = a0.z; As[ak0+3][ar0] = a0.w;
    As[ak1+0][ar1] = a1.x; As[ak1+1][ar1] = a1.y; As[ak1+2][ar1] = a1.z; As[ak1+3][ar1] = a1.w;
    Bs[ak0+0][ar0] = b0.x; Bs[ak0+1][ar0] = b0.y; Bs[ak0+2][ar0] = b0.z; Bs[ak0+3][ar0] = b0.w;
    Bs[ak1+0][ar1] = b1.x; Bs[ak1+1][ar1] = b1.y; Bs[ak1+2][ar1] = b1.z; Bs[ak1+3][ar1] = b1.w;
    __syncthreads();
    #pragma unroll
    for (int kk = 0; kk < 16; ++kk) {
      float af[8], bf[8];
      #pragma unroll
      for (int i = 0; i < 8; ++i) af[i] = As[kk][ti*8 + i];
      #pragma unroll
      for (int j = 0; j < 8; ++j) bf[j] = Bs[kk][tj*8 + j];
      #pragma unroll
      for (int i = 0; i < 8; ++i)
        #pragma unroll
        for (int j = 0; j < 8; ++j) acc[i][j] += af[i] * bf[j];
    }
  }

  float bv[8];
  #pragma unroll
  for (int jj = 0; jj < 8; ++jj) {
    int n = bcol + tj*8 + jj;
    float bb = 0.f;
    if (bias1) bb += bias1[n];
    if (bias2) bb += bias2[n];
    bv[jj] = bb;
  }
  #pragma unroll
  for (int i = 0; i < 8; ++i) {
    int m = brow + ti*8 + i;
    float* cp = C + (size_t)m * N + bcol + tj*8;
    float4 v0 = make_float4(acc[i][0]+bv[0], acc[i][1]+bv[1], acc[i][2]+bv[2], acc[i][3]+bv[3]);
    float4 v1 = make_float4(acc[i][4]+bv[4], acc[i][5]+bv[5], acc[i][6]+bv[6], acc[i][7]+bv[7]);
    *(float4*)cp = v0;
    *(float4*)(cp + 4) = v1;
  }
}

// ---------------------------------------------------------------------------
// Merged 2-layer persistent LSTM, lag-1 pipeline: combined step tt computes
// h0[tt+1] = LSTM0(h0[tt]) and h1[tt] = LSTM1(h1[tt-1], x=h0[tt]); ONE grid
// exchange serves both layers, Wih1 matvec fused (shares h0 LDS reads).
//
// Register budget (round-4 spill post-mortem): only Whh0 + Wih1 slices live
// in registers (32 float4 = 128 VGPR). Whh1 is STREAMED from global every
// step: per-XCD working set = 32 blocks x 64 KB = 2 MB -> L2-resident, ~0.5
// us/step chip-wide, overlapped with LDS dots. Peak regs ~190 -> no spill.
//
// Exchange (round-2-proven): RELAXED agent-scope atomics for all cross-block
// data (no cache-maintenance storms); h/flag stores ordered by s_waitcnt
// vmcnt(0); flattened poll (one flag per thread); h staged back via relaxed
// agent-scope 8B atomic loads (IF-fresh by construction).
// Co-residency: LDS 33 KB, grid 256 <= capacity -> no deadlock.
// ---------------------------------------------------------------------------
__global__ __launch_bounds__(256, 1) void lstm2_persist(
    const float* __restrict__ g0pre,  // [t][b][gate*1024+j], t-stride 16384
    const float* __restrict__ Whh0,   // (4096,1024)
    const float* __restrict__ Wih1,   // (4096,1024)
    const float* __restrict__ Whh1,   // (4096,1024)
    const float* __restrict__ bih1,
    const float* __restrict__ bhh1,
    float* __restrict__ h0seq,        // 513 slots of (4,1024)
    float* __restrict__ h1seq,        // 513 slots of (4,1024)
    unsigned* __restrict__ flag)      // 256 flags, zeroed by init_state
{
  __shared__ float hl0[4096];         // h0[tt]   [b][k]  (16 KB)
  __shared__ float hl1[4096];         // h1[tt-1] [b][k]  (16 KB)
  __shared__ float gsum[48][4];       // [row][b]: 0..15 Whh0, 16..31 Wih1, 32..47 Whh1

  const int tid = threadIdx.x;
  const int bid = blockIdx.x;
  const int rl = tid >> 4, ks = tid & 15;   // local row 0..15, k-split 0..15
  const int grow = (rl >> 2) * 1024 + bid * 4 + (rl & 3);  // gate*1024 + dim

  // --- one-time: Whh0/Wih1 slices into registers (interleaved: i*16+ks) ---
  float4 w0[16], wi1[16];
  {
    const float4* r0 = (const float4*)(Whh0 + (size_t)grow * 1024);
    const float4* r1 = (const float4*)(Wih1 + (size_t)grow * 1024);
    #pragma unroll
    for (int i = 0; i < 16; ++i) {
      w0[i]  = r0[i * 16 + ks];
      wi1[i] = r1[i * 16 + ks];
    }
  }
  // Whh1 slice stays in global, streamed (L2-resident) each step
  const float4* wg = (const float4*)(Whh1 + (size_t)grow * 1024);

  // h0[0] = h1[-1] = 0 in LDS
  {
    float4 z = make_float4(0.f, 0.f, 0.f, 0.f);
    float4* a = (float4*)hl0; float4* b = (float4*)hl1;
    #pragma unroll
    for (int i = 0; i < 4; ++i) { a[tid + 256*i] = z; b[tid + 256*i] = z; }
  }

  // gate-lane state: lanes 0..15 = layer0 (b=q>>2, dim=q&3), 16..31 = layer1
  float creg = 0.f;
  const int q = tid & 15, gb = q >> 2, gj = q & 3;
  float gpv0 = 0.f, gpv1 = 0.f, gpv2 = 0.f, gpv3 = 0.f;   // layer0 gpre slice
  float bs0 = 0.f, bs1 = 0.f, bs2 = 0.f, bs3 = 0.f;       // layer1 biases
  if (tid < 16) {
    const float* gp = g0pre + (size_t)gb * 4096 + bid * 4 + gj;
    gpv0 = gp[0]; gpv1 = gp[1024]; gpv2 = gp[2048]; gpv3 = gp[3072];
  } else if (tid < 32) {
    int o = bid * 4 + gj;
    bs0 = bih1[o]        + bhh1[o];
    bs1 = bih1[1024 + o] + bhh1[1024 + o];
    bs2 = bih1[2048 + o] + bhh1[2048 + o];
    bs3 = bih1[3072 + o] + bhh1[3072 + o];
  }
  __syncthreads();

  const float4* h04 = (const float4*)hl0;
  const float4* h14 = (const float4*)hl1;

  for (int tt = 0; tt <= 512; ++tt) {
    // --- phase A: Whh0.h0 and Wih1.h0 (register weights, shared x reads) ---
    float a00=0.f,a01=0.f,a02=0.f,a03=0.f;
    float a10=0.f,a11=0.f,a12=0.f,a13=0.f;
    #pragma unroll
    for (int i = 0; i < 16; ++i) {
      const int k4 = i * 16 + ks;
      float4 x0 = h04[k4], x1 = h04[256+k4], x2 = h04[512+k4], x3 = h04[768+k4];
      float4 w = w0[i];
      a00 += w.x*x0.x + w.y*x0.y + w.z*x0.z + w.w*x0.w;
      a01 += w.x*x1.x + w.y*x1.y + w.z*x1.z + w.w*x1.w;
      a02 += w.x*x2.x + w.y*x2.y + w.z*x2.z + w.w*x2.w;
      a03 += w.x*x3.x + w.y*x3.y + w.z*x3.z + w.w*x3.w;
      w = wi1[i];
      a10 += w.x*x0.x + w.y*x0.y + w.z*x0.z + w.w*x0.w;
      a11 += w.x*x1.x + w.y*x1.y + w.z*x1.z + w.w*x1.w;
      a12 += w.x*x2.x + w.y*x2.y + w.z*x2.z + w.w*x2.w;
      a13 += w.x*x3.x + w.y*x3.y + w.z*x3.z + w.w*x3.w;
    }
    // --- phase B: Whh1.h1 (weights streamed from global; L2-resident) ---
    float a20=0.f,a21=0.f,a22=0.f,a23=0.f;
    #pragma unroll
    for (int i = 0; i < 16; ++i) {
      const int k4 = i * 16 + ks;
      float4 w  = wg[k4];
      float4 y0 = h14[k4], y1 = h14[256+k4], y2 = h14[512+k4], y3 = h14[768+k4];
      a20 += w.x*y0.x + w.y*y0.y + w.z*y0.z + w.w*y0.w;
      a21 += w.x*y1.x + w.y*y1.y + w.z*y1.z + w.w*y1.w;
      a22 += w.x*y2.x + w.y*y2.y + w.z*y2.z + w.w*y2.w;
      a23 += w.x*y3.x + w.y*y3.y + w.z*y3.z + w.w*y3.w;
    }
    // reduce across the 16 ks-lanes (xor 8,4,2,1 stays in 16-lane groups)
    #pragma unroll
    for (int m = 8; m >= 1; m >>= 1) {
      a00 += __shfl_xor(a00, m, 64); a01 += __shfl_xor(a01, m, 64);
      a02 += __shfl_xor(a02, m, 64); a03 += __shfl_xor(a03, m, 64);
      a10 += __shfl_xor(a10, m, 64); a11 += __shfl_xor(a11, m, 64);
      a12 += __shfl_xor(a12, m, 64); a13 += __shfl_xor(a13, m, 64);
      a20 += __shfl_xor(a20, m, 64); a21 += __shfl_xor(a21, m, 64);
      a22 += __shfl_xor(a22, m, 64); a23 += __shfl_xor(a23, m, 64);
    }
    if (ks == 0) {
      *(float4*)&gsum[     rl][0] = make_float4(a00, a01, a02, a03);
      *(float4*)&gsum[16 + rl][0] = make_float4(a10, a11, a12, a13);
      *(float4*)&gsum[32 + rl][0] = make_float4(a20, a21, a22, a23);
    }
    __syncthreads();                               // gsum ready

    // --- gates + state + h stores (wave 0, lanes 0..31) ---
    if (tid < 16) {
      if (tt < 512) {
        float gi = gpv0 + gsum[     gj][gb];
        float gf = gpv1 + gsum[ 4 + gj][gb];
        float gg = gpv2 + gsum[ 8 + gj][gb];
        float go = gpv3 + gsum[12 + gj][gb];
        float c = sigmoidf(gf) * creg + sigmoidf(gi) * tanhf(gg);
        creg = c;
        float hv = sigmoidf(go) * tanhf(c);
        __hip_atomic_store(h0seq + (size_t)(tt + 1) * G4 + gb * 1024 + bid * 4 + gj,
                           hv, __ATOMIC_RELAXED, __HIP_MEMORY_SCOPE_AGENT);
      }
    } else if (tid < 32) {
      if (tt >= 1) {
        float gi = bs0 + gsum[16 + gj][gb] + gsum[32 + gj][gb];
        float gf = bs1 + gsum[20 + gj][gb] + gsum[36 + gj][gb];
        float gg = bs2 + gsum[24 + gj][gb] + gsum[40 + gj][gb];
        float go = bs3 + gsum[28 + gj][gb] + gsum[44 + gj][gb];
        float c = sigmoidf(gf) * creg + sigmoidf(gi) * tanhf(gg);
        creg = c;
        float hv = sigmoidf(go) * tanhf(c);
        __hip_atomic_store(h1seq + (size_t)tt * G4 + gb * 1024 + bid * 4 + gj,
                           hv, __ATOMIC_RELAXED, __HIP_MEMORY_SCOPE_AGENT);
      }
    }

    if (tt == 512) break;   // final h1[512] stored; kernel-end drains vmcnt

    // --- arrival (wave 0) + g0 prefetch + flattened poll (all threads) ---
    if (tid < 64) {
      asm volatile("s_waitcnt vmcnt(0)" ::: "memory");   // h stores acked at IF
      if (tid == 0)
        __hip_atomic_store(flag + bid, (unsigned)(tt + 1),
                           __ATOMIC_RELAXED, __HIP_MEMORY_SCOPE_AGENT);
    }
    if (tid < 16 && tt + 1 < 512) {   // prefetch next g0 slice (plain cached)
      const float* gp = g0pre + (size_t)(tt + 1) * 16384 + (size_t)gb * 4096 + bid * 4 + gj;
      gpv0 = gp[0]; gpv1 = gp[1024]; gpv2 = gp[2048]; gpv3 = gp[3072];
      asm volatile("" ::: "memory");
    }
    {
      const unsigned tgt = (unsigned)(tt + 1);
      for (;;) {
        unsigned f = __hip_atomic_load(flag + tid, __ATOMIC_RELAXED, __HIP_MEMORY_SCOPE_AGENT);
        if (__all(f >= tgt)) break;
      }
    }
    asm volatile("" ::: "memory");
    __syncthreads();                               // all 256 flags seen

    // --- stage h0[tt+1] and h1[tt] via bypass 8B atomic loads (IF-fresh) ---
    {
      const unsigned long long* s0 =
          (const unsigned long long*)(h0seq + (size_t)(tt + 1) * G4);
      unsigned long long* d0 = (unsigned long long*)hl0;
      #pragma unroll
      for (int i = 0; i < 8; ++i)
        d0[tid + 256*i] = __hip_atomic_load(s0 + tid + 256*i,
                                            __ATOMIC_RELAXED, __HIP_MEMORY_SCOPE_AGENT);
      if (tt >= 1) {
        const unsigned long long* s1 =
            (const unsigned long long*)(h1seq + (size_t)tt * G4);
        unsigned long long* d1 = (unsigned long long*)hl1;
        #pragma unroll
        for (int i = 0; i < 8; ++i)
          d1[tid + 256*i] = __hip_atomic_load(s1 + tid + 256*i,
                                              __ATOMIC_RELAXED, __HIP_MEMORY_SCOPE_AGENT);
      }
    }
    __syncthreads();                               // hl0/hl1 current
  }
}

// Per-row (b,t) stats over logits in d_out:
__global__ __launch_bounds__(256) void row_stats(
    const float* __restrict__ logits, float* __restrict__ rowA, float* __restrict__ rowE)
{
  const int m = blockIdx.x;
  const float* row = logits + (size_t)m * VV;
  __shared__ float red[8];
  const int tid = threadIdx.x;

  float mx = -3.0e38f;
  for (int v = tid; v < EOSI; v += 256) mx = fmaxf(mx, row[v]);
  for (int off = 32; off; off >>= 1) mx = fmaxf(mx, __shfl_down(mx, off, 64));
  if ((tid & 63) == 0) red[tid >> 6] = mx;
  __syncthreads();
  if (tid == 0) red[4] = fmaxf(fmaxf(red[0], red[1]), fmaxf(red[2], red[3]));
  __syncthreads();
  mx = red[4];

  float s = 0.f;
  for (int v = tid; v < EOSI; v += 256) s += expf(row[v] - mx);
  for (int off = 32; off; off >>= 1) s += __shfl_down(s, off, 64);
  if ((tid & 63) == 0) red[tid >> 6] = s;
  __syncthreads();

  if (tid == 0) {
    s = red[0] + red[1] + red[2] + red[3];
    float lse_v = mx + logf(s);
    float eos = row[EOSI];
    int t = m & 511;                         // m = b*512 + t
    float log_lb = (float)(t + 1) * LOG_BOUND;
    float log_eos_lb = -softplusf(eos);      // log_sigmoid(-eos)
    float log_eos_ub = -softplusf(-eos);     // log_sigmoid(eos)
    float shift = log_lb + log_eos_lb;
    float f_lb = -expm1f(log_lb);            // 1 - exp(log_lb)
    float log_lb_eos = logf(f_lb) + log_eos_lb;
    float lprob_eos = log_lb_eos + softplusf(log_eos_ub - log_lb_eos);
    float aa = shift, bb = lprob_eos;
    float lse2 = fmaxf(aa, bb) + log1pf(expf(-fabsf(aa - bb)));
    rowA[m] = lse_v + lse2 - shift;
    rowE[m] = lprob_eos - lse2;
  }
}

// out[m][v] = logit - rowA[m] for v < EOSI ; rowE[m] at v == EOSI. In-place, float4.
__global__ __launch_bounds__(256) void finalize(
    float* __restrict__ out, const float* __restrict__ rowA, const float* __restrict__ rowE)
{
  const int m = blockIdx.y;
  const int v4 = blockIdx.x * 256 + threadIdx.x;   // 8000 float4 per row
  if (v4 >= 8000) return;
  float4* rp = (float4*)(out + (size_t)m * VV);
  const float A = rowA[m];
  float4 p = rp[v4];
  p.x -= A; p.y -= A; p.z -= A; p.w -= A;
  if (v4 == 7999) p.w = rowE[m];
  rp[v4] = p;
}

extern "C" void kernel_launch(void* const* d_in, const int* in_sizes, int n_in,
                              void* d_out, int out_size, void* d_ws, size_t ws_size,
                              hipStream_t stream)
{
  const int*   tokens = (const int*)  d_in[0];
  const float* emb    = (const float*)d_in[1];
  const float* Wproj  = (const float*)d_in[2];
  const float* Wih0   = (const float*)d_in[3];
  const float* Whh0   = (const float*)d_in[4];
  const float* bih0   = (const float*)d_in[5];
  const float* bhh0   = (const float*)d_in[6];
  const float* Wih1   = (const float*)d_in[7];
  const float* Whh1   = (const float*)d_in[8];
  const float* bih1   = (const float*)d_in[9];
  const float* bhh1   = (const float*)d_in[10];
  float* out = (float*)d_out;

  // workspace layout (floats): ~50 MB total
  float* ws = (float*)d_ws;
  float* g0   = ws;                        // 2048 x 4096
  float* h0   = g0 + (size_t)2048*4096;    // 513 slots of (4,1024); slot 0 unused
  float* h1   = h0 + (size_t)513*4096;
  unsigned* flag = (unsigned*)(h1 + (size_t)513*4096);   // 256
  float* rowA = (float*)(flag + 256);      // 2048
  float* rowE = rowA + 2048;

  init_state<<<1, 256, 0, stream>>>(flag);

  // layer 0 input gates for all (t,b): emb[tokens] @ Wih0^T + bih0 + bhh0
  gemm_nt<<<dim3(32, 16), 256, 0, stream>>>(emb, Wih0, g0, 2048, 4096, 1024,
                                            bih0, bhh0, tokens, 1);

  // both LSTM layers, lag-1 pipelined, single persistent launch
  lstm2_persist<<<NBLK, 256, 0, stream>>>(g0, Whh0, Wih1, Whh1, bih1, bhh1,
                                          h0, h1, flag);

  // projection: logits into d_out, layout (b, t, v)
  gemm_nt<<<dim3(250, 16), 256, 0, stream>>>(h1, Wproj, out, 2048, 32000, 1024,
                                             nullptr, nullptr, nullptr, 2);

  row_stats<<<2048, 256, 0, stream>>>(out, rowA, rowE);
  finalize<<<dim3(32, 2048), 256, 0, stream>>>(out, rowA, rowE);
}